// Round 2
// baseline (476.652 us; speedup 1.0000x reference)
//
#include <hip/hip_runtime.h>

// Problem constants (from reference)
#define B_     8
#define L_DEC_ 256
#define V_     32000
#define L_SRC_ 512
#define V_EXT_ 32128

#define V4_    (V_ / 4)       // 8000 float4 per dist row
#define VE4_   (V_EXT_ / 4)   // 8032 float4 per out row
#define PAD4_  (VE4_ - V4_)   // 32 float4 of zero padding

// Native clang vector type: __builtin_nontemporal_load/store require a
// pointer to scalar/vector-of-scalar, not HIP's float4 struct.
typedef float f32x4 __attribute__((ext_vector_type(4)));

// Fused kernel, one block per (b,t) output row:
//   out[b,t,v] = p_gen[b,t]*dist[b,t,v] (v<V, else 0) + (1-p_gen[b,t])*copyp[b,t,v]
//   copyp[b,t,v] = sum_{s: pointer[b,s]==v} alpha[b,s,t]
//
// v2: no dense LDS accumulator. Stream the row (out = pg*dist), one barrier
// (its vmcnt(0) drain makes the stores visible at L2 before RMW), then 512
// direct global fp32 atomics for the sparse copy-scatter. 1 barrier instead
// of 6, zero LDS -> 4 blocks/CU instead of 2.
__global__ __launch_bounds__(512, 8) void copynet_fused(
    const float* __restrict__ dist,    // [B, L_DEC, V]
    const float* __restrict__ p_gen,   // [B, L_DEC, 1]
    const float* __restrict__ alph,    // [B, L_SRC, L_DEC]
    const int*   __restrict__ pointer, // [B, L_SRC]
    float* __restrict__ out)           // [B, L_DEC, V_EXT]
{
    const int row = blockIdx.x;        // b*L_DEC + t  (t fastest -> alpha L2 reuse)
    const int b   = row >> 8;          // / L_DEC
    const int t   = row & (L_DEC_ - 1);
    const int tid = threadIdx.x;       // 0..511

    const float pg   = p_gen[row];     // wave-uniform broadcast
    const float coef = 1.0f - pg;

    // Hoist this thread's scatter operands so the loads fly during the stream.
    // s == tid (L_SRC == blockDim == 512); alpha read is strided (1 KB) but the
    // whole alpha tensor is 4 MB and reused across 256 t-rows -> L2/L3 resident.
    const int   sIdx = b * L_SRC_ + tid;
    const int   v    = pointer[sIdx];
    const float val  = coef * alph[(size_t)sIdx * L_DEC_ + t];

    const f32x4* dist4 = (const f32x4*)(dist + (size_t)row * V_);
    f32x4*       out4  = (f32x4*)(out + (size_t)row * V_EXT_);

    // Pass 1: pure stream, out = pg*dist. dist is read-once -> nontemporal
    // loads keep L2 capacity for the out lines the atomics will RMW.
    for (int i = tid; i < V4_; i += 512) {
        f32x4 d = __builtin_nontemporal_load(dist4 + i);
        d *= pg;
        out4[i] = d;
    }
    // Pad region [V, V_EXT): copyp-only, init to 0.
    if (tid < PAD4_) {
        f32x4 z = {0.f, 0.f, 0.f, 0.f};
        out4[V4_ + tid] = z;
    }

    // __syncthreads lowers to s_waitcnt vmcnt(0) lgkmcnt(0) + s_barrier:
    // all row stores are at the L2 coherence point before any atomic RMW
    // of the same addresses from other lanes of this block.
    __syncthreads();

    // Pass 2: sparse copy-scatter, one device-scope fp32 atomic per source
    // position (~451 distinct lines / row, ~4 collisions / row).
    atomicAdd(out + (size_t)row * V_EXT_ + v, val);
}

extern "C" void kernel_launch(void* const* d_in, const int* in_sizes, int n_in,
                              void* d_out, int out_size, void* d_ws, size_t ws_size,
                              hipStream_t stream)
{
    const float* dist    = (const float*)d_in[0]; // (B, L_DEC, V)
    const float* p_gen   = (const float*)d_in[1]; // (B, L_DEC, 1)
    const float* alph    = (const float*)d_in[2]; // (B, L_SRC, L_DEC)
    // d_in[3] = batch_vocab (shape only)
    const int*   pointer = (const int*)d_in[4];   // (B, L_SRC)
    float* out = (float*)d_out;                   // (B, L_DEC, V_EXT)

    copynet_fused<<<B_ * L_DEC_, 512, 0, stream>>>(dist, p_gen, alph, pointer, out);
}

// Round 3
// 439.388 us; speedup vs baseline: 1.0848x; 1.0848x over previous
//
#include <hip/hip_runtime.h>

// Problem constants (from reference)
#define B_     8
#define L_DEC_ 256
#define V_     32000
#define L_SRC_ 512
#define V_EXT_ 32128

#define V4_    (V_ / 4)        // 8000 float4 per dist row
#define VE4_   (V_EXT_ / 4)    // 8032 float4 per out row
#define NITER_ ((VE4_ + 511) / 512)  // 16 streaming iterations

// Native clang vector type (nontemporal builtins reject HIP's float4 struct).
typedef float f32x4 __attribute__((ext_vector_type(4)));

// Fused kernel, one block per (b,t) output row:
//   out[b,t,v] = p_gen*dist[v] (v<V, else 0) + (1-p_gen)*copyp[v]
//   copyp[v]   = sum_{s: pointer[b,s]==v} alpha[b,s,t]
//
// v3: single streaming pass; the sparse 512-entry scatter is merged into the
// write itself. The thread writing float4 slot g4 is tid = g4 % 512, so the
// 512 (v,val) pairs are bucketed into per-owner-thread linked lists in LDS
// (8 KB total), then each thread applies its (avg 1, Poisson) entries while
// streaming. No dense LDS accumulator (v1: 62.75 KB, 6 barriers, 2 passes),
// no global atomic RMW (v2: HBM line fetch per atomic, +38 us).
__global__ __launch_bounds__(512, 8) void copynet_fused(
    const float* __restrict__ dist,    // [B, L_DEC, V]
    const float* __restrict__ p_gen,   // [B, L_DEC, 1]
    const float* __restrict__ alph,    // [B, L_SRC, L_DEC]
    const int*   __restrict__ pointer, // [B, L_SRC]
    float* __restrict__ out)           // [B, L_DEC, V_EXT]
{
    __shared__ int   head[512];   // per-owner-thread list head (-1 = empty)
    __shared__ int   nxt[512];    // linkage, indexed by entry id (= s = tid)
    __shared__ int   key[512];    // vocab index v of entry
    __shared__ float sval[512];   // (1-pg)*alpha value of entry

    const int row = blockIdx.x;   // b*L_DEC + t  (t fastest -> alpha L2 reuse)
    const int b   = row >> 8;     // / L_DEC
    const int t   = row & (L_DEC_ - 1);
    const int tid = threadIdx.x;  // 0..511

    const float pg   = p_gen[row];
    const float coef = 1.0f - pg;

    // This thread's scatter entry: s == tid (L_SRC == blockDim == 512).
    // alpha[b] is 512 KB, reused across 256 t-rows -> L2-resident after first.
    const int   sIdx = b * L_SRC_ + tid;
    const int   v    = pointer[sIdx];
    const float val  = coef * alph[(size_t)sIdx * L_DEC_ + t];

    // Build per-owner lists: owner thread of vocab v is (v/4) % 512.
    head[tid] = -1;
    __syncthreads();
    key[tid]  = v;
    sval[tid] = val;
    const int owner = (v >> 2) & 511;
    nxt[tid] = atomicExch(&head[owner], tid);   // lock-free stack push (ds op)
    __syncthreads();

    const int myHead = head[tid];               // immutable after barrier
    const f32x4* dist4 = (const f32x4*)(dist + (size_t)row * V_);
    f32x4*       out4  = (f32x4*)(out + (size_t)row * V_EXT_);

    // Single streaming pass, coalesced 16 B/lane. dist read-once and out
    // write-once -> nontemporal on both, keeping L2 for alpha/pointer reuse.
    for (int k = 0; k < NITER_; ++k) {
        const int i = tid + (k << 9);
        if (i >= VE4_) break;                   // only trims the last iteration
        f32x4 r;
        if (i < V4_) {
            r = __builtin_nontemporal_load(dist4 + i) * pg;
        } else {
            r = (f32x4){0.f, 0.f, 0.f, 0.f};    // pad region: copyp only
        }
        // Apply this thread's scatter entries that land in slot i.
        for (int e = myHead; e != -1; e = nxt[e]) {
            const int kv = key[e];
            if ((kv >> 2) == i) {
                const float a = sval[e];
                const int   c = kv & 3;
                r.x += (c == 0) ? a : 0.f;
                r.y += (c == 1) ? a : 0.f;
                r.z += (c == 2) ? a : 0.f;
                r.w += (c == 3) ? a : 0.f;
            }
        }
        __builtin_nontemporal_store(r, out4 + i);
    }
}

extern "C" void kernel_launch(void* const* d_in, const int* in_sizes, int n_in,
                              void* d_out, int out_size, void* d_ws, size_t ws_size,
                              hipStream_t stream)
{
    const float* dist    = (const float*)d_in[0]; // (B, L_DEC, V)
    const float* p_gen   = (const float*)d_in[1]; // (B, L_DEC, 1)
    const float* alph    = (const float*)d_in[2]; // (B, L_SRC, L_DEC)
    // d_in[3] = batch_vocab (shape only)
    const int*   pointer = (const int*)d_in[4];   // (B, L_SRC)
    float* out = (float*)d_out;                   // (B, L_DEC, V_EXT)

    copynet_fused<<<B_ * L_DEC_, 512, 0, stream>>>(dist, p_gen, alph, pointer, out);
}